// Round 3
// baseline (3900.742 us; speedup 1.0000x reference)
//
#include <hip/hip_runtime.h>
#include <hip/hip_bf16.h>

typedef __attribute__((ext_vector_type(2))) _Float16 half2_t;
typedef __attribute__((ext_vector_type(8))) _Float16 half8_t;

#define RD 256
#define NLAGS 512
#define NPAST 128
#define NT 512   // threads per block

// ---------------------------------------------------------------------------
// Kernel 1: randomized-signature scan (batch-independent), one block.
// A1 (f32) in registers; A2 as f16-hi (regs) + f16-lo residual (LDS) -> ~f32.
// ---------------------------------------------------------------------------
__global__ __launch_bounds__(512, 2) void rsig_kernel(
    const float* __restrict__ xp,
    const float* __restrict__ A1, const float* __restrict__ A2,
    const float* __restrict__ xi1, const float* __restrict__ xi2,
    const float* __restrict__ W2h, const float* __restrict__ b2h,
    const float* __restrict__ W2o, const float* __restrict__ b2o,
    float* __restrict__ rsig_out)
{
    const int tid = threadIdx.x;
    const int i = tid >> 1;      // output row 0..255
    const int h = tid & 1;       // K-half
    const int sw = tid & 15;

    __shared__ __align__(16) ushort a2lo[NT * 128];   // 128 KB (512 thr x 128 ushort)
    __shared__ __align__(16) float Z[2][RD];
    __shared__ float dx[NPAST];
    __shared__ float hh[32];

    float4 a1f[32];
    half2_t a2h[64];
    {
        const float* s1 = A1 + i * RD + h * 128;
        const float* s2 = A2 + i * RD + h * 128;
#pragma unroll
        for (int v = 0; v < 32; ++v) a1f[v] = ((const float4*)s1)[v];
#pragma unroll
        for (int c = 0; c < 16; ++c) {
            float4 a = ((const float4*)s2)[2 * c];
            float4 d = ((const float4*)s2)[2 * c + 1];
            _Float16 h0 = (_Float16)a.x, h1 = (_Float16)a.y, h2 = (_Float16)a.z, h3 = (_Float16)a.w;
            _Float16 h4 = (_Float16)d.x, h5 = (_Float16)d.y, h6 = (_Float16)d.z, h7 = (_Float16)d.w;
            a2h[4 * c + 0] = half2_t{h0, h1};
            a2h[4 * c + 1] = half2_t{h2, h3};
            a2h[4 * c + 2] = half2_t{h4, h5};
            a2h[4 * c + 3] = half2_t{h6, h7};
            half8_t lo;
            lo[0] = (_Float16)(a.x - (float)h0); lo[1] = (_Float16)(a.y - (float)h1);
            lo[2] = (_Float16)(a.z - (float)h2); lo[3] = (_Float16)(a.w - (float)h3);
            lo[4] = (_Float16)(d.x - (float)h4); lo[5] = (_Float16)(d.y - (float)h5);
            lo[6] = (_Float16)(d.z - (float)h6); lo[7] = (_Float16)(d.w - (float)h7);
            *(half8_t*)&a2lo[tid * 128 + ((c ^ sw) << 3)] = lo;
        }
    }
    const float x1 = xi1[i];
    const float x2 = xi2[i];

    if (tid < NPAST - 1) dx[tid] = xp[tid + 1] - xp[tid];
    if (tid < RD) Z[0][tid] = 0.0f;
    __syncthreads();

    int cur = 0;
    for (int t = 0; t < NPAST - 1; ++t) {
        const float4* Zb = (const float4*)&Z[cur][h * 128];
        const float zcur = Z[cur][i];
        const float dxt = dx[t];
        float acc1 = 0.f, acc2h_ = 0.f, acc2l_ = 0.f;
#pragma unroll
        for (int c = 0; c < 16; ++c) {
            float4 r0 = Zb[2 * c], r1 = Zb[2 * c + 1];
            float4 w0 = a1f[2 * c], w1 = a1f[2 * c + 1];
            half8_t lo = *(const half8_t*)&a2lo[tid * 128 + ((c ^ sw) << 3)];
            half2_t p0 = a2h[4 * c + 0], p1 = a2h[4 * c + 1];
            half2_t p2 = a2h[4 * c + 2], p3 = a2h[4 * c + 3];
            acc1 = fmaf(w0.x, r0.x, acc1);
            acc1 = fmaf(w0.y, r0.y, acc1);
            acc1 = fmaf(w0.z, r0.z, acc1);
            acc1 = fmaf(w0.w, r0.w, acc1);
            acc1 = fmaf(w1.x, r1.x, acc1);
            acc1 = fmaf(w1.y, r1.y, acc1);
            acc1 = fmaf(w1.z, r1.z, acc1);
            acc1 = fmaf(w1.w, r1.w, acc1);
            acc2h_ = fmaf((float)p0.x, r0.x, acc2h_);
            acc2h_ = fmaf((float)p0.y, r0.y, acc2h_);
            acc2h_ = fmaf((float)p1.x, r0.z, acc2h_);
            acc2h_ = fmaf((float)p1.y, r0.w, acc2h_);
            acc2h_ = fmaf((float)p2.x, r1.x, acc2h_);
            acc2h_ = fmaf((float)p2.y, r1.y, acc2h_);
            acc2h_ = fmaf((float)p3.x, r1.z, acc2h_);
            acc2h_ = fmaf((float)p3.y, r1.w, acc2h_);
            acc2l_ = fmaf((float)lo[0], r0.x, acc2l_);
            acc2l_ = fmaf((float)lo[1], r0.y, acc2l_);
            acc2l_ = fmaf((float)lo[2], r0.z, acc2l_);
            acc2l_ = fmaf((float)lo[3], r0.w, acc2l_);
            acc2l_ = fmaf((float)lo[4], r1.x, acc2l_);
            acc2l_ = fmaf((float)lo[5], r1.y, acc2l_);
            acc2l_ = fmaf((float)lo[6], r1.z, acc2l_);
            acc2l_ = fmaf((float)lo[7], r1.w, acc2l_);
        }
        float acc1s = acc1 + __shfl_xor(acc1, 1, 64);
        float acc2 = acc2h_ + acc2l_;
        float acc2s = acc2 + __shfl_xor(acc2, 1, 64);
        float zn = zcur + tanhf(acc1s + x1) + tanhf(acc2s + x2) * dxt;
        if (h == 0) Z[cur ^ 1][i] = zn;
        __syncthreads();
        cur ^= 1;
    }

    // readout MLP: hidden 32, output 226 (f32 weights from global)
    if (tid < 32) {
        float a = b2h[tid];
        const float* wrow = W2h + tid * RD;
        for (int k = 0; k < RD; ++k) a = fmaf(wrow[k], Z[cur][k], a);
        hh[tid] = tanhf(a);
    }
    __syncthreads();
    if (tid < RD - 30) {
        float a = b2o[tid];
        const float* wrow = W2o + tid * 32;
        for (int k = 0; k < 32; ++k) a = fmaf(wrow[k], hh[k], a);
        rsig_out[tid] = a;
    }
}

// ---------------------------------------------------------------------------
// Kernel 2: main SDE scan. One block per batch row.
// rho1*B1 (f32) in regs; rho3*B2 as f16-hi (regs) + f16-lo residual (LDS).
// R f32 double-buffered in LDS; 1 barrier per step.
// ---------------------------------------------------------------------------
__global__ __launch_bounds__(512, 2) void sde_main_kernel(
    const float* __restrict__ inc,       // (B, 512)
    const float* __restrict__ Vn,        // (B, 32)
    const float* __restrict__ W1h, const float* __restrict__ b1h,
    const float* __restrict__ W1o, const float* __restrict__ b1o,
    const float* __restrict__ rho1p, const float* __restrict__ rho2p,
    const float* __restrict__ rho3p, const float* __restrict__ rho4p,
    const float* __restrict__ B1, const float* __restrict__ B2,
    const float* __restrict__ lam1, const float* __restrict__ lam2,
    const float* __restrict__ Wr, const float* __restrict__ brp,
    const float* __restrict__ rsig,      // ws, 226 floats
    float* __restrict__ out)             // (B, 512)
{
    const int tid  = threadIdx.x;
    const int b    = blockIdx.x;
    const int i    = tid >> 1;   // output row 0..255
    const int h    = tid & 1;    // K-half
    const int lane = tid & 63;
    const int w    = tid >> 6;   // wave 0..7
    const int sw   = tid & 15;

    __shared__ __align__(16) ushort b2lo[NT * 128];   // 128 KB (512 thr x 128 ushort)
    __shared__ __align__(16) float R[2][RD];
    __shared__ __align__(16) float inc_lds[NLAGS];
    __shared__ float red[2][8];
    __shared__ float hv[32];

    const float rho1 = *rho1p, rho2 = *rho2p, rho3 = *rho3p, rho4 = *rho4p;

    float4 b1f[32];
    half2_t b2h_[64];
    {
        const float* s1 = B1 + i * RD + h * 128;
        const float* s2 = B2 + i * RD + h * 128;
#pragma unroll
        for (int v = 0; v < 32; ++v) {
            float4 a = ((const float4*)s1)[v];
            a.x *= rho1; a.y *= rho1; a.z *= rho1; a.w *= rho1;
            b1f[v] = a;
        }
#pragma unroll
        for (int c = 0; c < 16; ++c) {
            float4 a = ((const float4*)s2)[2 * c];
            float4 d = ((const float4*)s2)[2 * c + 1];
            float q0 = rho3 * a.x, q1 = rho3 * a.y, q2 = rho3 * a.z, q3 = rho3 * a.w;
            float q4 = rho3 * d.x, q5 = rho3 * d.y, q6 = rho3 * d.z, q7 = rho3 * d.w;
            _Float16 h0 = (_Float16)q0, h1 = (_Float16)q1, h2 = (_Float16)q2, h3 = (_Float16)q3;
            _Float16 h4 = (_Float16)q4, h5 = (_Float16)q5, h6 = (_Float16)q6, h7 = (_Float16)q7;
            b2h_[4 * c + 0] = half2_t{h0, h1};
            b2h_[4 * c + 1] = half2_t{h2, h3};
            b2h_[4 * c + 2] = half2_t{h4, h5};
            b2h_[4 * c + 3] = half2_t{h6, h7};
            half8_t lo;
            lo[0] = (_Float16)(q0 - (float)h0); lo[1] = (_Float16)(q1 - (float)h1);
            lo[2] = (_Float16)(q2 - (float)h2); lo[3] = (_Float16)(q3 - (float)h3);
            lo[4] = (_Float16)(q4 - (float)h4); lo[5] = (_Float16)(q5 - (float)h5);
            lo[6] = (_Float16)(q6 - (float)h6); lo[7] = (_Float16)(q7 - (float)h7);
            *(half8_t*)&b2lo[tid * 128 + ((c ^ sw) << 3)] = lo;
        }
    }
    const float c1  = rho2 * lam1[i];
    const float c2  = rho4 * lam2[i];
    const float wri = Wr[i];
    const float brv = *brp;

    // prologue: increments to LDS, initial condition R0 = [rsig ; V]
    inc_lds[tid] = inc[b * NLAGS + tid];
    if (tid < 32) {
        float a = b1h[tid];
        const float* wrow = W1h + tid * 32;
        const float* vn = Vn + b * 32;
        for (int k = 0; k < 32; ++k) a = fmaf(wrow[k], vn[k], a);
        hv[tid] = tanhf(a);
    }
    if (tid < RD - 30) R[0][tid] = rsig[tid];
    __syncthreads();
    if (tid == 0) inc_lds[1] = inc_lds[0] + inc_lds[1];   // dW[0] = inc0 + inc1
    if (tid < 30) {
        float a = b1o[tid];
        const float* wrow = W1o + tid * 32;
        for (int k = 0; k < 32; ++k) a = fmaf(wrow[k], hv[k], a);
        R[0][(RD - 30) + tid] = a;
    }
    __syncthreads();

    // readout of R0 -> out[b, 0]
    {
        float p = R[0][i] * wri;          // both pair-lanes hold p_i
        p += __shfl_xor(p, 2, 64);
        p += __shfl_xor(p, 4, 64);
        p += __shfl_xor(p, 8, 64);
        p += __shfl_xor(p, 16, 64);
        p += __shfl_xor(p, 32, 64);       // lane0: sum over even lanes = wave's 32 rows
        if (lane == 0) red[0][w] = p;
    }
    __syncthreads();
    if (tid == 0) {
        float s = brv;
        for (int q = 0; q < 8; ++q) s += red[0][q];
        out[b * NLAGS] = s;
    }

    int cur = 0;
    for (int t = 0; t < NLAGS - 1; ++t) {
        const float4* Rb = (const float4*)&R[cur][h * 128];
        const float rcur = R[cur][i];
        const float dwt = inc_lds[t + 1];
        float acc1 = 0.f, acc2h_ = 0.f, acc2l_ = 0.f;
#pragma unroll
        for (int c = 0; c < 16; ++c) {
            float4 r0 = Rb[2 * c], r1 = Rb[2 * c + 1];
            float4 w0 = b1f[2 * c], w1 = b1f[2 * c + 1];
            half8_t lo = *(const half8_t*)&b2lo[tid * 128 + ((c ^ sw) << 3)];
            half2_t p0 = b2h_[4 * c + 0], p1 = b2h_[4 * c + 1];
            half2_t p2 = b2h_[4 * c + 2], p3 = b2h_[4 * c + 3];
            acc1 = fmaf(w0.x, r0.x, acc1);
            acc1 = fmaf(w0.y, r0.y, acc1);
            acc1 = fmaf(w0.z, r0.z, acc1);
            acc1 = fmaf(w0.w, r0.w, acc1);
            acc1 = fmaf(w1.x, r1.x, acc1);
            acc1 = fmaf(w1.y, r1.y, acc1);
            acc1 = fmaf(w1.z, r1.z, acc1);
            acc1 = fmaf(w1.w, r1.w, acc1);
            acc2h_ = fmaf((float)p0.x, r0.x, acc2h_);
            acc2h_ = fmaf((float)p0.y, r0.y, acc2h_);
            acc2h_ = fmaf((float)p1.x, r0.z, acc2h_);
            acc2h_ = fmaf((float)p1.y, r0.w, acc2h_);
            acc2h_ = fmaf((float)p2.x, r1.x, acc2h_);
            acc2h_ = fmaf((float)p2.y, r1.y, acc2h_);
            acc2h_ = fmaf((float)p3.x, r1.z, acc2h_);
            acc2h_ = fmaf((float)p3.y, r1.w, acc2h_);
            acc2l_ = fmaf((float)lo[0], r0.x, acc2l_);
            acc2l_ = fmaf((float)lo[1], r0.y, acc2l_);
            acc2l_ = fmaf((float)lo[2], r0.z, acc2l_);
            acc2l_ = fmaf((float)lo[3], r0.w, acc2l_);
            acc2l_ = fmaf((float)lo[4], r1.x, acc2l_);
            acc2l_ = fmaf((float)lo[5], r1.y, acc2l_);
            acc2l_ = fmaf((float)lo[6], r1.z, acc2l_);
            acc2l_ = fmaf((float)lo[7], r1.w, acc2l_);
        }
        float acc1s = acc1 + __shfl_xor(acc1, 1, 64);
        float acc2 = acc2h_ + acc2l_;
        float acc2s = acc2 + __shfl_xor(acc2, 1, 64);
        float drift = tanhf(acc1s + c1);
        float dif   = tanhf(acc2s + c2);
        float rn = rcur + drift + dif * dwt;
        if (h == 0) R[cur ^ 1][i] = rn;
        float p = rn * wri;
        p += __shfl_xor(p, 2, 64);
        p += __shfl_xor(p, 4, 64);
        p += __shfl_xor(p, 8, 64);
        p += __shfl_xor(p, 16, 64);
        p += __shfl_xor(p, 32, 64);
        if (lane == 0) red[(t + 1) & 1][w] = p;
        __syncthreads();
        if (tid == 0) {
            float s = brv;
            for (int q = 0; q < 8; ++q) s += red[(t + 1) & 1][q];
            out[b * NLAGS + t + 1] = s;
        }
        cur ^= 1;
    }
}

extern "C" void kernel_launch(void* const* d_in, const int* in_sizes, int n_in,
                              void* d_out, int out_size, void* d_ws, size_t ws_size,
                              hipStream_t stream) {
    // setup_inputs() order
    const float* x_past  = (const float*)d_in[2];
    const float* V_noise = (const float*)d_in[3];
    const float* inc     = (const float*)d_in[4];
    const float* W1h     = (const float*)d_in[5];
    const float* b1h     = (const float*)d_in[6];
    const float* W1o     = (const float*)d_in[7];
    const float* b1o     = (const float*)d_in[8];
    const float* W2h     = (const float*)d_in[9];
    const float* b2h     = (const float*)d_in[10];
    const float* W2o     = (const float*)d_in[11];
    const float* b2o     = (const float*)d_in[12];
    const float* rho1    = (const float*)d_in[13];
    const float* rho2    = (const float*)d_in[14];
    const float* rho3    = (const float*)d_in[15];
    const float* rho4    = (const float*)d_in[16];
    const float* B1      = (const float*)d_in[17];
    const float* B2      = (const float*)d_in[18];
    const float* lam1    = (const float*)d_in[19];
    const float* lam2    = (const float*)d_in[20];
    const float* A1      = (const float*)d_in[21];
    const float* A2      = (const float*)d_in[22];
    const float* xi1     = (const float*)d_in[23];
    const float* xi2     = (const float*)d_in[24];
    const float* Wr      = (const float*)d_in[25];
    const float* br      = (const float*)d_in[26];

    float* rsig_ws = (float*)d_ws;   // 226 floats

    rsig_kernel<<<1, 512, 0, stream>>>(x_past, A1, A2, xi1, xi2,
                                       W2h, b2h, W2o, b2o, rsig_ws);

    sde_main_kernel<<<256, 512, 0, stream>>>(inc, V_noise, W1h, b1h, W1o, b1o,
                                             rho1, rho2, rho3, rho4,
                                             B1, B2, lam1, lam2, Wr, br,
                                             rsig_ws, (float*)d_out);
}